// Round 10
// baseline (1077.873 us; speedup 1.0000x reference)
//
#include <hip/hip_runtime.h>
#include <math.h>

// Problem constants
#define B   16
#define N   128
#define E   4
#define H   64
#define M   64
#define IN_ 32
#define T   32

typedef _Float16 f16;
typedef f16  f16x8 __attribute__((ext_vector_type(8)));
typedef float f32x4 __attribute__((ext_vector_type(4)));

#define MFMA16(a, b, c) __builtin_amdgcn_mfma_f32_16x16x32_f16(a, b, c, 0, 0, 0)

// fp16 weight pack offsets (halves)
#define OFF_W1T   0
#define OFF_W2T   32768
#define OFF_WE3H  65536
#define OFF_RI0   589824
#define OFF_RI1   602112
#define OFF_RI2   634880
#define OFF_RI3   667648
#define OFF_RJ0   671744
#define OFF_RJ1   679936
#define OFF_RJ2   712704
#define OFF_RJ3   745472
#define WPACK_SZ  749568

#define GRID_BLKS 256   // 1 block/CU guaranteed resident (256 CUs) -> safe SW barrier

// Shared-memory union; sizeof = 71680 (pg) -> fits 160KB/CU at 1 block/CU.
union SmemU {
    struct { float xl[64][4]; f16 y1[64][136]; f16 y2[64][264]; } e;   // 52224
    struct { f16 Al[128][72]; f16 Bl[128][72]; f16 Ol[128][136]; } pg; // 71680
    struct { float prt[4][64]; float hsum[64]; float bias[64]; } bi;   // 1536
    struct { f16 Al[128][136]; f16 Bl[64][136]; } mm;                  // 52224
    struct { f16 Xl[32][104]; f16 A1[32][136]; f16 A2[32][264]; float Gl[32][36]; } ro;
    struct { float m_lds[64]; float h_lds[64]; float gi[192]; float gh[192]; } gr;
    float fin[32];
};

struct Params {
    const float *h_in, *am;
    const int   *g_sz;
    const float *We0, *be0, *We1, *be1, *We2, *be2, *We3, *be3;
    const float *Wih, *Whh, *bih, *bhh;
    const float *bi0, *bi1, *bi2, *bi3, *bj0, *bj1, *bj2, *bj3;
    const float *Wi0, *Wi1, *Wi2, *Wi3, *Wj0, *Wj1, *Wj2, *Wj3;
    f16   *f, *P2, *h16, *hin16, *wp;
    float *msg, *h, *contrib, *out;
    int   *bar;
};

// ---- software global barrier (R9 post-mortem analysis) -------------------
// release: __syncthreads drains this block's stores (vmcnt0); __threadfence
// emits agent-scope buffer_wbl2 (flush XCD L2 to coherence point).
// acquire: after all blocks arrive, __threadfence emits buffer_inv so
// subsequent normal loads miss stale per-XCD L2/L1 lines.
__device__ __forceinline__ void gbar(int* bar, int ph, int tid) {
    __syncthreads();
    __threadfence();
    if (tid == 0) {
        atomicAdd(&bar[ph], 1);
        while (atomicAdd(&bar[ph], 0) < GRID_BLKS)
            __builtin_amdgcn_s_sleep(2);
    }
    __syncthreads();
    __threadfence();
}

// ===================== task bodies (R9-proven) ============================

__device__ void edge_task(SmemU& su, int tid, int tile, const Params& p) {
    int lane = tid & 63, wv = tid >> 6;
    long long g0 = (long long)tile * 64;
    const f16* W1t = p.wp + OFF_W1T;
    const f16* W2t = p.wp + OFF_W2T;

    ((float*)su.e.xl)[tid] = p.am[g0 * 4 + tid];
    __syncthreads();

    {   // layer 1: K=4, VALU
        int j = tid & 127, e0 = (tid >> 7) * 32;
        float w0 = p.We0[j], w1 = p.We0[128 + j], w2 = p.We0[256 + j], w3 = p.We0[384 + j];
        float bb = p.be0[j];
        #pragma unroll 8
        for (int e = e0; e < e0 + 32; ++e) {
            float v = bb + su.e.xl[e][0] * w0 + su.e.xl[e][1] * w1
                         + su.e.xl[e][2] * w2 + su.e.xl[e][3] * w3;
            su.e.y1[e][j] = (f16)fmaxf(v, 0.f);
        }
    }
    __syncthreads();

    int m = lane & 15, q = lane >> 4;

    {   // layer 2
        f32x4 acc[4][4];
        #pragma unroll
        for (int ct = 0; ct < 4; ++ct)
            #pragma unroll
            for (int rt = 0; rt < 4; ++rt) acc[ct][rt] = (f32x4){0.f, 0.f, 0.f, 0.f};
        #pragma unroll
        for (int s = 0; s < 4; ++s) {
            int k0 = s * 32 + q * 8;
            f16x8 afr[4], bfr[4];
            #pragma unroll
            for (int rt = 0; rt < 4; ++rt)
                afr[rt] = *(const f16x8*)&su.e.y1[rt * 16 + m][k0];
            #pragma unroll
            for (int ct = 0; ct < 4; ++ct) {
                int n = (wv * 4 + ct) * 16 + m;
                bfr[ct] = *(const f16x8*)(W1t + n * 128 + k0);
            }
            #pragma unroll
            for (int ct = 0; ct < 4; ++ct)
                #pragma unroll
                for (int rt = 0; rt < 4; ++rt)
                    acc[ct][rt] = MFMA16(afr[rt], bfr[ct], acc[ct][rt]);
        }
        #pragma unroll
        for (int ct = 0; ct < 4; ++ct) {
            int n = (wv * 4 + ct) * 16 + m;
            float bb = p.be1[n];
            #pragma unroll
            for (int rt = 0; rt < 4; ++rt)
                #pragma unroll
                for (int r = 0; r < 4; ++r) {
                    int row = rt * 16 + q * 4 + r;
                    su.e.y2[row][n] = (f16)fmaxf(acc[ct][rt][r] + bb, 0.f);
                }
        }
    }
    __syncthreads();

    {   // layer 3 (out-stage back into y1)
        f32x4 acc[2][4];
        #pragma unroll
        for (int ct = 0; ct < 2; ++ct)
            #pragma unroll
            for (int rt = 0; rt < 4; ++rt) acc[ct][rt] = (f32x4){0.f, 0.f, 0.f, 0.f};
        #pragma unroll
        for (int s = 0; s < 8; ++s) {
            int k0 = s * 32 + q * 8;
            f16x8 afr[4], bfr[2];
            #pragma unroll
            for (int rt = 0; rt < 4; ++rt)
                afr[rt] = *(const f16x8*)&su.e.y2[rt * 16 + m][k0];
            #pragma unroll
            for (int ct = 0; ct < 2; ++ct) {
                int n = (wv * 2 + ct) * 16 + m;
                bfr[ct] = *(const f16x8*)(W2t + n * 256 + k0);
            }
            #pragma unroll
            for (int ct = 0; ct < 2; ++ct)
                #pragma unroll
                for (int rt = 0; rt < 4; ++rt)
                    acc[ct][rt] = MFMA16(afr[rt], bfr[ct], acc[ct][rt]);
        }
        #pragma unroll
        for (int ct = 0; ct < 2; ++ct) {
            int n = (wv * 2 + ct) * 16 + m;
            float bb = p.be2[n];
            #pragma unroll
            for (int rt = 0; rt < 4; ++rt)
                #pragma unroll
                for (int r = 0; r < 4; ++r) {
                    int row = rt * 16 + q * 4 + r;
                    su.e.y1[row][n] = (f16)fmaxf(acc[ct][rt][r] + bb, 0.f);
                }
        }
    }
    __syncthreads();

    #pragma unroll
    for (int j = 0; j < 4; ++j) {
        int c = tid + j * 256;
        int e = c >> 4, pp = c & 15;
        *(uint4*)(p.f + (g0 + e) * 128 + pp * 8) = *(const uint4*)&su.e.y1[e][pp * 8];
    }
}

__device__ void pgemm_task(SmemU& su, int tid, int ob, int nt, const Params& p) {
    int lane = tid & 63, wv = tid >> 6;
    const f16* We3h = p.wp + OFF_WE3H;

    #pragma unroll
    for (int j = 0; j < 4; ++j) {
        int c = tid + j * 256;
        int row = c >> 3, pp = c & 7;
        *(uint4*)&su.pg.Al[row][pp * 8] =
            *(const uint4*)(p.h16 + (size_t)(nt * 128 + row) * 64 + pp * 8);
    }
    #pragma unroll
    for (int j = 0; j < 4; ++j) {
        int c = tid + j * 256;
        int k = c >> 3, pp = c & 7;
        *(uint4*)&su.pg.Bl[k][pp * 8] =
            *(const uint4*)(We3h + ((size_t)(k * 64 + ob)) * 64 + pp * 8);
    }
    __syncthreads();

    int m = lane & 15, q = lane >> 4;
    f32x4 acc[2][8];
    #pragma unroll
    for (int ct = 0; ct < 2; ++ct)
        #pragma unroll
        for (int rt = 0; rt < 8; ++rt) acc[ct][rt] = (f32x4){0.f, 0.f, 0.f, 0.f};
    #pragma unroll
    for (int s = 0; s < 2; ++s) {
        int k0 = s * 32 + q * 8;
        f16x8 afr[8], bfr[2];
        #pragma unroll
        for (int rt = 0; rt < 8; ++rt)
            afr[rt] = *(const f16x8*)&su.pg.Al[rt * 16 + m][k0];
        #pragma unroll
        for (int ct = 0; ct < 2; ++ct)
            bfr[ct] = *(const f16x8*)&su.pg.Bl[(wv * 2 + ct) * 16 + m][k0];
        #pragma unroll
        for (int ct = 0; ct < 2; ++ct)
            #pragma unroll
            for (int rt = 0; rt < 8; ++rt)
                acc[ct][rt] = MFMA16(afr[rt], bfr[ct], acc[ct][rt]);
    }
    #pragma unroll
    for (int ct = 0; ct < 2; ++ct) {
        int col = (wv * 2 + ct) * 16 + m;
        #pragma unroll
        for (int rt = 0; rt < 8; ++rt)
            #pragma unroll
            for (int r = 0; r < 4; ++r)
                su.pg.Ol[rt * 16 + q * 4 + r][col] = (f16)acc[ct][rt][r];
    }
    __syncthreads();
    #pragma unroll
    for (int j = 0; j < 8; ++j) {
        int c = tid + j * 256;
        int row = c >> 4, pp = c & 15;
        *(uint4*)(p.P2 + ((size_t)(nt * 128 + row) * 64 + ob) * 128 + pp * 8) =
            *(const uint4*)&su.pg.Ol[row][pp * 8];
    }
}

// bias task now initializes the full msg accumulator: msg[b,v,o] = bias[b,o]
__device__ void bias_task(SmemU& su, int tid, int b, const Params& p) {
    int i = tid & 63, wq = tid >> 6;
    float s = 0.f;
    for (int w = wq; w < N; w += 4) s += p.h[((size_t)(b * N + w)) * H + i];
    su.bi.prt[wq][i] = s;
    __syncthreads();
    if (tid < 64)
        su.bi.hsum[tid] = su.bi.prt[0][tid] + su.bi.prt[1][tid]
                        + su.bi.prt[2][tid] + su.bi.prt[3][tid];
    __syncthreads();
    if (tid < 64) {
        float sb = 0.f;
        #pragma unroll 4
        for (int ii = 0; ii < H; ++ii) sb += p.be3[tid * H + ii] * su.bi.hsum[ii];
        su.bi.bias[tid] = sb;
    }
    __syncthreads();
    for (int idx = tid; idx < N * M; idx += 256)
        p.msg[(size_t)b * N * M + idx] = su.bi.bias[idx & 63];
}

// msg task: atomicAdd partial sums directly into msg (R2-proven pattern)
__device__ void msg_task(SmemU& su, int tid, int ws, int b, const Params& p) {
    int lane = tid & 63, wv = tid >> 6;
    int m = lane & 15, q = lane >> 4;

    f32x4 acc[2][4];
    #pragma unroll
    for (int rt = 0; rt < 2; ++rt)
        #pragma unroll
        for (int ct = 0; ct < 4; ++ct) acc[rt][ct] = (f32x4){0.f, 0.f, 0.f, 0.f};

    for (int wi = 0; wi < 4; ++wi) {
        int w = ws * 4 + wi;
        #pragma unroll
        for (int j = 0; j < 8; ++j) {
            int c = tid + j * 256;
            int v = c >> 4, pp = c & 15;
            *(uint4*)&su.mm.Al[v][pp * 8] =
                *(const uint4*)(p.f + (((size_t)(b * 128 + v) * 128 + w) * 128) + pp * 8);
        }
        #pragma unroll
        for (int j = 0; j < 4; ++j) {
            int c = tid + j * 256;
            int o = c >> 4, pp = c & 15;
            *(uint4*)&su.mm.Bl[o][pp * 8] =
                *(const uint4*)(p.P2 + (((size_t)(b * 128 + w) * 64 + o) * 128) + pp * 8);
        }
        __syncthreads();
        #pragma unroll
        for (int s = 0; s < 4; ++s) {
            int k0 = s * 32 + q * 8;
            f16x8 afr[2], bfr[4];
            #pragma unroll
            for (int rt = 0; rt < 2; ++rt)
                afr[rt] = *(const f16x8*)&su.mm.Al[(wv * 2 + rt) * 16 + m][k0];
            #pragma unroll
            for (int ct = 0; ct < 4; ++ct)
                bfr[ct] = *(const f16x8*)&su.mm.Bl[ct * 16 + m][k0];
            #pragma unroll
            for (int rt = 0; rt < 2; ++rt)
                #pragma unroll
                for (int ct = 0; ct < 4; ++ct)
                    acc[rt][ct] = MFMA16(afr[rt], bfr[ct], acc[rt][ct]);
        }
        __syncthreads();
    }
    #pragma unroll
    for (int rt = 0; rt < 2; ++rt)
        #pragma unroll
        for (int ct = 0; ct < 4; ++ct) {
            int o = ct * 16 + m;
            #pragma unroll
            for (int r = 0; r < 4; ++r) {
                int v = (wv * 2 + rt) * 16 + q * 4 + r;
                atomicAdd(p.msg + (size_t)(b * 128 + v) * 64 + o, acc[rt][ct][r]);
            }
        }
}

__device__ void gru_node(SmemU& su, int tid, int bv, const Params& p) {
    int b = bv >> 7, v = bv & 127;
    if (tid < 64) su.gr.m_lds[tid] = p.msg[(size_t)bv * 64 + tid];
    else if (tid < 128) su.gr.h_lds[tid - 64] = p.h[bv * 64 + (tid - 64)];
    __syncthreads();
    if (tid < 192) {
        float si = p.bih[tid], sh = p.bhh[tid];
        const float* wi = p.Wih + tid * M;
        const float* wh = p.Whh + tid * H;
        #pragma unroll 4
        for (int k = 0; k < M; ++k) si += wi[k] * su.gr.m_lds[k];
        #pragma unroll 4
        for (int k = 0; k < H; ++k) sh += wh[k] * su.gr.h_lds[k];
        su.gr.gi[tid] = si;
        su.gr.gh[tid] = sh;
    }
    __syncthreads();
    if (tid < 64) {
        float r = 1.f / (1.f + expf(-(su.gr.gi[tid] + su.gr.gh[tid])));
        float z = 1.f / (1.f + expf(-(su.gr.gi[64 + tid] + su.gr.gh[64 + tid])));
        float n = tanhf(su.gr.gi[128 + tid] + r * su.gr.gh[128 + tid]);
        float hv = (1.f - z) * n + z * su.gr.h_lds[tid];
        float maskf = (v < p.g_sz[b]) ? 1.f : 0.f;
        hv *= maskf;
        p.h[bv * 64 + tid] = hv;
        p.h16[bv * 64 + tid] = (f16)hv;
    }
    __syncthreads();
}

__device__ void readout_task(SmemU& su, int tid, int blk, const Params& p) {
    const f16* Ri0 = p.wp + OFF_RI0; const f16* Ri1 = p.wp + OFF_RI1;
    const f16* Ri2 = p.wp + OFF_RI2; const f16* Ri3 = p.wp + OFF_RI3;
    const f16* Rj0 = p.wp + OFF_RJ0; const f16* Rj1 = p.wp + OFF_RJ1;
    const f16* Rj2 = p.wp + OFF_RJ2; const f16* Rj3 = p.wp + OFF_RJ3;
    int lane = tid & 63, wv = tid >> 6;
    int m = lane & 15, q = lane >> 4;
    int r0 = blk * 32;

    {
        int row = tid >> 3, pp = tid & 7;
        *(uint4*)&su.ro.Xl[row][pp * 8] =
            *(const uint4*)(p.h16 + (size_t)(r0 + row) * 64 + pp * 8);
        if (tid < 128) {
            int row2 = tid >> 2, p2 = tid & 3;
            *(uint4*)&su.ro.Xl[row2][64 + p2 * 8] =
                *(const uint4*)(p.hin16 + (size_t)(r0 + row2) * 32 + p2 * 8);
        }
    }
    __syncthreads();

    // i-chain L0
    {
        f32x4 acc[2][2];
        #pragma unroll
        for (int ct = 0; ct < 2; ++ct)
            #pragma unroll
            for (int rt = 0; rt < 2; ++rt) acc[ct][rt] = (f32x4){0.f, 0.f, 0.f, 0.f};
        #pragma unroll
        for (int s = 0; s < 3; ++s) {
            int k0 = s * 32 + q * 8;
            f16x8 afr[2], bfr[2];
            #pragma unroll
            for (int rt = 0; rt < 2; ++rt)
                afr[rt] = *(const f16x8*)&su.ro.Xl[rt * 16 + m][k0];
            #pragma unroll
            for (int ct = 0; ct < 2; ++ct)
                bfr[ct] = *(const f16x8*)(Ri0 + ((wv * 2 + ct) * 16 + m) * 96 + k0);
            #pragma unroll
            for (int ct = 0; ct < 2; ++ct)
                #pragma unroll
                for (int rt = 0; rt < 2; ++rt)
                    acc[ct][rt] = MFMA16(afr[rt], bfr[ct], acc[ct][rt]);
        }
        #pragma unroll
        for (int ct = 0; ct < 2; ++ct) {
            int n = (wv * 2 + ct) * 16 + m;
            float bb = p.bi0[n];
            #pragma unroll
            for (int rt = 0; rt < 2; ++rt)
                #pragma unroll
                for (int r = 0; r < 4; ++r)
                    su.ro.A1[rt * 16 + q * 4 + r][n] = (f16)fmaxf(acc[ct][rt][r] + bb, 0.f);
        }
    }
    __syncthreads();

    // i-chain L1
    {
        f32x4 acc[4][2];
        #pragma unroll
        for (int ct = 0; ct < 4; ++ct)
            #pragma unroll
            for (int rt = 0; rt < 2; ++rt) acc[ct][rt] = (f32x4){0.f, 0.f, 0.f, 0.f};
        #pragma unroll
        for (int s = 0; s < 4; ++s) {
            int k0 = s * 32 + q * 8;
            f16x8 afr[2], bfr[4];
            #pragma unroll
            for (int rt = 0; rt < 2; ++rt)
                afr[rt] = *(const f16x8*)&su.ro.A1[rt * 16 + m][k0];
            #pragma unroll
            for (int ct = 0; ct < 4; ++ct)
                bfr[ct] = *(const f16x8*)(Ri1 + ((wv * 4 + ct) * 16 + m) * 128 + k0);
            #pragma unroll
            for (int ct = 0; ct < 4; ++ct)
                #pragma unroll
                for (int rt = 0; rt < 2; ++rt)
                    acc[ct][rt] = MFMA16(afr[rt], bfr[ct], acc[ct][rt]);
        }
        #pragma unroll
        for (int ct = 0; ct < 4; ++ct) {
            int n = (wv * 4 + ct) * 16 + m;
            float bb = p.bi1[n];
            #pragma unroll
            for (int rt = 0; rt < 2; ++rt)
                #pragma unroll
                for (int r = 0; r < 4; ++r)
                    su.ro.A2[rt * 16 + q * 4 + r][n] = (f16)fmaxf(acc[ct][rt][r] + bb, 0.f);
        }
    }
    __syncthreads();

    // i-chain L2
    {
        f32x4 acc[2][2];
        #pragma unroll
        for (int ct = 0; ct < 2; ++ct)
            #pragma unroll
            for (int rt = 0; rt < 2; ++rt) acc[ct][rt] = (f32x4){0.f, 0.f, 0.f, 0.f};
        #pragma unroll
        for (int s = 0; s < 8; ++s) {
            int k0 = s * 32 + q * 8;
            f16x8 afr[2], bfr[2];
            #pragma unroll
            for (int rt = 0; rt < 2; ++rt)
                afr[rt] = *(const f16x8*)&su.ro.A2[rt * 16 + m][k0];
            #pragma unroll
            for (int ct = 0; ct < 2; ++ct)
                bfr[ct] = *(const f16x8*)(Ri2 + ((wv * 2 + ct) * 16 + m) * 256 + k0);
            #pragma unroll
            for (int ct = 0; ct < 2; ++ct)
                #pragma unroll
                for (int rt = 0; rt < 2; ++rt)
                    acc[ct][rt] = MFMA16(afr[rt], bfr[ct], acc[ct][rt]);
        }
        __syncthreads();
        #pragma unroll
        for (int ct = 0; ct < 2; ++ct) {
            int n = (wv * 2 + ct) * 16 + m;
            float bb = p.bi2[n];
            #pragma unroll
            for (int rt = 0; rt < 2; ++rt)
                #pragma unroll
                for (int r = 0; r < 4; ++r)
                    su.ro.A1[rt * 16 + q * 4 + r][n] = (f16)fmaxf(acc[ct][rt][r] + bb, 0.f);
        }
    }
    __syncthreads();

    // i-chain L3 -> gate
    if (wv < 2) {
        f32x4 acc[2];
        acc[0] = (f32x4){0.f, 0.f, 0.f, 0.f};
        acc[1] = (f32x4){0.f, 0.f, 0.f, 0.f};
        int n = wv * 16 + m;
        #pragma unroll
        for (int s = 0; s < 4; ++s) {
            int k0 = s * 32 + q * 8;
            f16x8 bfr = *(const f16x8*)(Ri3 + n * 128 + k0);
            #pragma unroll
            for (int rt = 0; rt < 2; ++rt) {
                f16x8 afr = *(const f16x8*)&su.ro.A1[rt * 16 + m][k0];
                acc[rt] = MFMA16(afr, bfr, acc[rt]);
            }
        }
        float bb = p.bi3[n];
        #pragma unroll
        for (int rt = 0; rt < 2; ++rt)
            #pragma unroll
            for (int r = 0; r < 4; ++r)
                su.ro.Gl[rt * 16 + q * 4 + r][n] = 1.f / (1.f + expf(-(acc[rt][r] + bb)));
    }
    __syncthreads();

    // j-chain L0
    {
        f32x4 acc[2][2];
        #pragma unroll
        for (int ct = 0; ct < 2; ++ct)
            #pragma unroll
            for (int rt = 0; rt < 2; ++rt) acc[ct][rt] = (f32x4){0.f, 0.f, 0.f, 0.f};
        #pragma unroll
        for (int s = 0; s < 2; ++s) {
            int k0 = s * 32 + q * 8;
            f16x8 afr[2], bfr[2];
            #pragma unroll
            for (int rt = 0; rt < 2; ++rt)
                afr[rt] = *(const f16x8*)&su.ro.Xl[rt * 16 + m][k0];
            #pragma unroll
            for (int ct = 0; ct < 2; ++ct)
                bfr[ct] = *(const f16x8*)(Rj0 + ((wv * 2 + ct) * 16 + m) * 64 + k0);
            #pragma unroll
            for (int ct = 0; ct < 2; ++ct)
                #pragma unroll
                for (int rt = 0; rt < 2; ++rt)
                    acc[ct][rt] = MFMA16(afr[rt], bfr[ct], acc[ct][rt]);
        }
        __syncthreads();
        #pragma unroll
        for (int ct = 0; ct < 2; ++ct) {
            int n = (wv * 2 + ct) * 16 + m;
            float bb = p.bj0[n];
            #pragma unroll
            for (int rt = 0; rt < 2; ++rt)
                #pragma unroll
                for (int r = 0; r < 4; ++r)
                    su.ro.A1[rt * 16 + q * 4 + r][n] = (f16)fmaxf(acc[ct][rt][r] + bb, 0.f);
        }
    }
    __syncthreads();

    // j-chain L1
    {
        f32x4 acc[4][2];
        #pragma unroll
        for (int ct = 0; ct < 4; ++ct)
            #pragma unroll
            for (int rt = 0; rt < 2; ++rt) acc[ct][rt] = (f32x4){0.f, 0.f, 0.f, 0.f};
        #pragma unroll
        for (int s = 0; s < 4; ++s) {
            int k0 = s * 32 + q * 8;
            f16x8 afr[2], bfr[4];
            #pragma unroll
            for (int rt = 0; rt < 2; ++rt)
                afr[rt] = *(const f16x8*)&su.ro.A1[rt * 16 + m][k0];
            #pragma unroll
            for (int ct = 0; ct < 4; ++ct)
                bfr[ct] = *(const f16x8*)(Rj1 + ((wv * 4 + ct) * 16 + m) * 128 + k0);
            #pragma unroll
            for (int ct = 0; ct < 4; ++ct)
                #pragma unroll
                for (int rt = 0; rt < 2; ++rt)
                    acc[ct][rt] = MFMA16(afr[rt], bfr[ct], acc[ct][rt]);
        }
        #pragma unroll
        for (int ct = 0; ct < 4; ++ct) {
            int n = (wv * 4 + ct) * 16 + m;
            float bb = p.bj1[n];
            #pragma unroll
            for (int rt = 0; rt < 2; ++rt)
                #pragma unroll
                for (int r = 0; r < 4; ++r)
                    su.ro.A2[rt * 16 + q * 4 + r][n] = (f16)fmaxf(acc[ct][rt][r] + bb, 0.f);
        }
    }
    __syncthreads();

    // j-chain L2
    {
        f32x4 acc[2][2];
        #pragma unroll
        for (int ct = 0; ct < 2; ++ct)
            #pragma unroll
            for (int rt = 0; rt < 2; ++rt) acc[ct][rt] = (f32x4){0.f, 0.f, 0.f, 0.f};
        #pragma unroll
        for (int s = 0; s < 8; ++s) {
            int k0 = s * 32 + q * 8;
            f16x8 afr[2], bfr[2];
            #pragma unroll
            for (int rt = 0; rt < 2; ++rt)
                afr[rt] = *(const f16x8*)&su.ro.A2[rt * 16 + m][k0];
            #pragma unroll
            for (int ct = 0; ct < 2; ++ct)
                bfr[ct] = *(const f16x8*)(Rj2 + ((wv * 2 + ct) * 16 + m) * 256 + k0);
            #pragma unroll
            for (int ct = 0; ct < 2; ++ct)
                #pragma unroll
                for (int rt = 0; rt < 2; ++rt)
                    acc[ct][rt] = MFMA16(afr[rt], bfr[ct], acc[ct][rt]);
        }
        __syncthreads();
        #pragma unroll
        for (int ct = 0; ct < 2; ++ct) {
            int n = (wv * 2 + ct) * 16 + m;
            float bb = p.bj2[n];
            #pragma unroll
            for (int rt = 0; rt < 2; ++rt)
                #pragma unroll
                for (int r = 0; r < 4; ++r)
                    su.ro.A1[rt * 16 + q * 4 + r][n] = (f16)fmaxf(acc[ct][rt][r] + bb, 0.f);
        }
    }
    __syncthreads();

    // j-chain L3 + combine
    if (wv < 2) {
        f32x4 acc[2];
        acc[0] = (f32x4){0.f, 0.f, 0.f, 0.f};
        acc[1] = (f32x4){0.f, 0.f, 0.f, 0.f};
        int n = wv * 16 + m;
        #pragma unroll
        for (int s = 0; s < 4; ++s) {
            int k0 = s * 32 + q * 8;
            f16x8 bfr = *(const f16x8*)(Rj3 + n * 128 + k0);
            #pragma unroll
            for (int rt = 0; rt < 2; ++rt) {
                f16x8 afr = *(const f16x8*)&su.ro.A1[rt * 16 + m][k0];
                acc[rt] = MFMA16(afr, bfr, acc[rt]);
            }
        }
        float bb = p.bj3[n];
        #pragma unroll
        for (int rt = 0; rt < 2; ++rt)
            #pragma unroll
            for (int r = 0; r < 4; ++r) {
                int row = rt * 16 + q * 4 + r;
                int rg = r0 + row;
                int b = rg >> 7, v = rg & 127;
                float maskf = (v < p.g_sz[b]) ? 1.f : 0.f;
                p.contrib[(size_t)rg * T + n] = maskf * su.ro.Gl[row][n] * (acc[rt][r] + bb);
            }
    }
    __syncthreads();
}

__device__ void finalize_task(SmemU& su, int tid, int b, const Params& p) {
    if (tid < T) {
        float s = 0.f;
        for (int v = 0; v < N; ++v) s += p.contrib[(b * N + v) * T + tid];
        su.fin[tid] = s;
    }
    __syncthreads();
    if (tid < T) {
        float mx = su.fin[0];
        for (int i = 1; i < T; ++i) mx = fmaxf(mx, su.fin[i]);
        float se = 0.f;
        for (int i = 0; i < T; ++i) se += expf(su.fin[i] - mx);
        p.out[b * T + tid] = su.fin[tid] - mx - logf(se);
    }
    __syncthreads();
}

// ===================== the persistent mega kernel =========================
__global__ __launch_bounds__(256) void mega_kernel(Params p) {
    __shared__ SmemU su;
    int tid = threadIdx.x;
    int bid = blockIdx.x;
    int gidx = bid * 256 + tid;

    // P0: pad h + weight pack (grid-stride)
    for (int idx = gidx; idx < B * N * H; idx += GRID_BLKS * 256) {
        int i  = idx & (H - 1);
        int bn = idx >> 6;
        float v = (i < IN_) ? p.h_in[bn * IN_ + i] : 0.f;
        p.h[idx] = v;
        p.h16[idx] = (f16)v;
        if (i < IN_) p.hin16[bn * IN_ + i] = (f16)v;
    }
    for (int idx = gidx; idx < WPACK_SZ; idx += GRID_BLKS * 256) {
        f16* wp = p.wp;
        if (idx < OFF_W2T) {
            int j = idx >> 7, k = idx & 127;
            wp[idx] = (f16)p.We1[k * 256 + j];
        } else if (idx < OFF_WE3H) {
            int t = idx - OFF_W2T;
            int j = t >> 8, k = t & 255;
            wp[idx] = (f16)p.We2[k * 128 + j];
        } else if (idx < OFF_RI0) {
            wp[idx] = (f16)p.We3[idx - OFF_WE3H];
        } else if (idx < OFF_RI1) {
            int t = idx - OFF_RI0;
            int n = t / 96, c = t % 96;
            wp[idx] = (f16)p.Wi0[c * 128 + n];
        } else if (idx < OFF_RI2) {
            int t = idx - OFF_RI1;
            int n = t >> 7, k = t & 127;
            wp[idx] = (f16)p.Wi1[k * 256 + n];
        } else if (idx < OFF_RI3) {
            int t = idx - OFF_RI2;
            int n = t >> 8, k = t & 255;
            wp[idx] = (f16)p.Wi2[k * 128 + n];
        } else if (idx < OFF_RJ0) {
            int t = idx - OFF_RI3;
            int n = t >> 7, k = t & 127;
            wp[idx] = (f16)p.Wi3[k * 32 + n];
        } else if (idx < OFF_RJ1) {
            int t = idx - OFF_RJ0;
            int n = t >> 6, c = t & 63;
            wp[idx] = (f16)p.Wj0[c * 128 + n];
        } else if (idx < OFF_RJ2) {
            int t = idx - OFF_RJ1;
            int n = t >> 7, k = t & 127;
            wp[idx] = (f16)p.Wj1[k * 256 + n];
        } else if (idx < OFF_RJ3) {
            int t = idx - OFF_RJ2;
            int n = t >> 8, k = t & 255;
            wp[idx] = (f16)p.Wj2[k * 128 + n];
        } else {
            int t = idx - OFF_RJ3;
            int n = t >> 7, k = t & 127;
            wp[idx] = (f16)p.Wj3[k * 32 + n];
        }
    }
    int ph = 0;
    gbar(p.bar, ph++, tid);

    for (int l = 0; l < 3; ++l) {
        // phase A: p_gemm + bias-init(msg) (+ edge on l==0)
        int ntask = (l == 0) ? (4096 + 1024 + 16) : (1024 + 16);
        for (int t = bid; t < ntask; t += GRID_BLKS) {
            if (l == 0) {
                if (t < 4096)       edge_task(su, tid, t, p);
                else if (t < 5120) { int u = t - 4096; pgemm_task(su, tid, u & 63, u >> 6, p); }
                else                bias_task(su, tid, t - 5120, p);
            } else {
                if (t < 1024)       pgemm_task(su, tid, t & 63, t >> 6, p);
                else                bias_task(su, tid, t - 1024, p);
            }
            __syncthreads();
        }
        gbar(p.bar, ph++, tid);

        // phase B: msg accumulate (atomicAdd)
        for (int t = bid; t < 512; t += GRID_BLKS) {
            msg_task(su, tid, t & 31, t >> 5, p);
            __syncthreads();
        }
        gbar(p.bar, ph++, tid);

        // phase C: GRU
        for (int t = bid; t < 2048; t += GRID_BLKS)
            gru_node(su, tid, t, p);
        gbar(p.bar, ph++, tid);
    }

    // readout
    for (int t = bid; t < 64; t += GRID_BLKS) {
        readout_task(su, tid, t, p);
        __syncthreads();
    }
    gbar(p.bar, ph++, tid);

    // finalize
    for (int t = bid; t < 16; t += GRID_BLKS)
        finalize_task(su, tid, t, p);
}

// ===================== host side ==========================================
extern "C" void kernel_launch(void* const* d_in, const int* in_sizes, int n_in,
                              void* d_out, int out_size, void* d_ws, size_t ws_size,
                              hipStream_t stream) {
    (void)in_sizes; (void)n_in; (void)out_size; (void)ws_size;
    Params p;
    p.h_in = (const float*)d_in[0];
    p.am   = (const float*)d_in[1];
    p.g_sz = (const int*)d_in[2];
    p.We0 = (const float*)d_in[3];  p.be0 = (const float*)d_in[4];
    p.We1 = (const float*)d_in[5];  p.be1 = (const float*)d_in[6];
    p.We2 = (const float*)d_in[7];  p.be2 = (const float*)d_in[8];
    p.We3 = (const float*)d_in[9];  p.be3 = (const float*)d_in[10];
    p.Wih = (const float*)d_in[11]; p.Whh = (const float*)d_in[12];
    p.bih = (const float*)d_in[13]; p.bhh = (const float*)d_in[14];
    p.Wi0 = (const float*)d_in[15]; p.bi0 = (const float*)d_in[16];
    p.Wj0 = (const float*)d_in[17]; p.bj0 = (const float*)d_in[18];
    p.Wi1 = (const float*)d_in[19]; p.bi1 = (const float*)d_in[20];
    p.Wj1 = (const float*)d_in[21]; p.bj1 = (const float*)d_in[22];
    p.Wi2 = (const float*)d_in[23]; p.bi2 = (const float*)d_in[24];
    p.Wj2 = (const float*)d_in[25]; p.bj2 = (const float*)d_in[26];
    p.Wi3 = (const float*)d_in[27]; p.bi3 = (const float*)d_in[28];
    p.Wj3 = (const float*)d_in[29]; p.bj3 = (const float*)d_in[30];
    p.out = (float*)d_out;

    // workspace layout (~99 MB): barriers first (memset target)
    p.bar   = (int*)d_ws;                                  // 64 ints (zeroed)
    p.f     = (f16*)((char*)d_ws + 1024);                  // 33554432 halves
    p.P2    = p.f + (size_t)33554432;                      // 16777216 halves
    p.msg   = (float*)(p.P2 + (size_t)16777216);           // 131072 floats
    p.h     = p.msg + 131072;                              // 131072
    p.contrib = p.h + 131072;                              // 65536
    p.h16   = (f16*)(p.contrib + 65536);                   // 131072 halves
    p.hin16 = p.h16 + 131072;                              // 65536 halves
    p.wp    = p.hin16 + 65536;                             // 749568 halves

    hipMemsetAsync(d_ws, 0, 1024, stream);                 // zero barrier counters
    mega_kernel<<<GRID_BLKS, 256, 0, stream>>>(p);
}